// Round 8
// baseline (203.893 us; speedup 1.0000x reference)
//
#include <hip/hip_runtime.h>
#include <hip/hip_fp16.h>
#include <math.h>

typedef unsigned short u16;
typedef __attribute__((ext_vector_type(8))) _Float16 half8;
typedef __attribute__((ext_vector_type(4))) float f32x4;

__device__ __forceinline__ u16 f2h(float f){ __half h=__float2half(f); u16 r; __builtin_memcpy(&r,&h,2); return r; }
__device__ __forceinline__ float h2f(u16 u){ __half h; __builtin_memcpy(&h,&u,2); return __half2float(h); }

#define SYNC1 do{ __builtin_amdgcn_sched_barrier(0); __builtin_amdgcn_s_barrier(); \
    asm volatile("s_waitcnt lgkmcnt(0)" ::: "memory"); __builtin_amdgcn_sched_barrier(0); \
    __builtin_amdgcn_s_setprio(1); }while(0)
#define SYNC2 do{ __builtin_amdgcn_s_setprio(0); __builtin_amdgcn_sched_barrier(0); \
    __builtin_amdgcn_s_barrier(); }while(0)

// 256x256 tile, 8 waves (512 thr), BK=64, 8-phase schedule (T3+T4+T5+T2).
// LDS 128KB: 2 K-tile buffers x (A 256x64 + B 256x64) f16. Per iteration:
// 2 K-tiles (t0=2i buf0, t1=2i+1 buf1), 4 phases each:
//   ph1..4 compute t0: reads {a-half0+b-half0 | b-half1 | a-half1 | -}
//   ph5..8 compute t1: same pattern
// Stages (1 half-tile = 2 gload_lds/wave per phase):
//   ph1,2: A(t1) -> buf1-A      (buf1-A last read ph7 of iter i-1)
//   ph3,4: B(t0+2) -> buf0-B    (buf0-B last read ph2)
//   ph5,6: A(t0+2) -> buf0-A    (buf0-A last read ph3)
//   ph7,8: B(t1+2) -> buf1-B    (buf1-B last read ph6)
// vmcnt(4) at ph4/ph8 (counted, never 0 mid-loop; 0 on last iter): pins
// everything but the 2 most recent half-tiles landed. Every (read, re-stage)
// pair is separated by >=1 s_barrier after the reader's lgkmcnt(0).
// LDS bank swizzle: 16B chunk c at row r holds global chunk c^(r&7); reads
// XOR the same -> 2-way conflicts only (free).
// EPI: 0=f32, 1=f16, 2=f16 hi/lo split (cols c, c+1024). BIASM: 0/1=col/2=row.
template<int EPI, int BIASM, bool AWRAP>
__device__ __forceinline__ void gemm8(
    const u16* __restrict__ A, const u16* __restrict__ B,
    const float* __restrict__ bias,
    float* __restrict__ of, u16* __restrict__ oh,
    int by, int bx, int lda, int ldb, int ldc, int K, u16* sh)
{
    const int tid  = threadIdx.x;
    const int lane = tid & 63, wv = tid >> 6;
    const int wr = (wv >> 2) * 128;      // 2 M-groups of waves
    const int wc = (wv & 3) * 64;        // 4 N-groups
    const int row0 = by * 256, col0 = bx * 256;
    const int lr = lane & 15, hi = lane >> 4;

    f32x4 acc[8][4];
#pragma unroll
    for (int m = 0; m < 8; m++)
#pragma unroll
        for (int n = 0; n < 4; n++) acc[m][n] = (f32x4){0.f, 0.f, 0.f, 0.f};

    // stage one 128-row half-tile of op (0=A,1=B) for K-tile kt
    auto STG = [&](int op, int kt, int half){
        const u16* G = op ? B : A;
        const int  ld = op ? ldb : lda;
        const int  rb = (op ? col0 : row0) + half * 128;
        int k0 = kt << 6;
        if (AWRAP && op == 0) k0 &= 1023;
        u16* dst = sh + ((kt & 1) << 15) + (op << 14) + (half << 13);
#pragma unroll
        for (int p = 0; p < 2; ++p){
            const int lin = tid + p * 512;
            const int r  = lin >> 3;                  // 0..127
            const int ch = (lin & 7) ^ (r & 7);       // pre-swizzled source chunk
            const u16* g = G + (size_t)(rb + r) * ld + k0 + ch * 8;
            __builtin_amdgcn_global_load_lds(
                (__attribute__((address_space(1))) void*)g,
                (__attribute__((address_space(3))) void*)(dst + (size_t)lin * 8), 16, 0, 0);
        }
    };
    // register subtile reads (swizzled): a-half mh (4 m-frags x 2 ks), b-half nh
    auto LDA_ = [&](half8* a, int kt, int mh){
        const u16* base = sh + ((kt & 1) << 15);
#pragma unroll
        for (int mi = 0; mi < 4; ++mi)
#pragma unroll
            for (int ks = 0; ks < 2; ++ks){
                const int r = wr + (mh * 4 + mi) * 16 + lr;
                a[mi * 2 + ks] = *(const half8*)&base[(size_t)r * 64 + (((hi + ks * 4) ^ (lr & 7)) * 8)];
            }
    };
    auto LDB_ = [&](half8* b, int kt, int nh){
        const u16* base = sh + ((kt & 1) << 15) + 16384;
#pragma unroll
        for (int ni = 0; ni < 2; ++ni)
#pragma unroll
            for (int ks = 0; ks < 2; ++ks){
                const int r = wc + (nh * 2 + ni) * 16 + lr;
                b[ni * 2 + ks] = *(const half8*)&base[(size_t)r * 64 + (((hi + ks * 4) ^ (lr & 7)) * 8)];
            }
    };
    auto MM = [&](half8* a, half8* b, int mh, int nh){
#pragma unroll
        for (int mi = 0; mi < 4; ++mi)
#pragma unroll
            for (int ni = 0; ni < 2; ++ni)
#pragma unroll
                for (int ks = 0; ks < 2; ++ks)
                    acc[mh * 4 + mi][nh * 2 + ni] = __builtin_amdgcn_mfma_f32_16x16x32_f16(
                        a[mi * 2 + ks], b[ni * 2 + ks], acc[mh * 4 + mi][nh * 2 + ni], 0, 0, 0);
    };

    const int NKT = K >> 6, NIT = NKT >> 1;
    // prologue: KT0 (all 4 half-tiles) + B(KT1); leave B(KT1) in flight
    STG(1, 0, 0); STG(1, 0, 1); STG(0, 0, 0); STG(0, 0, 1);
    STG(1, 1, 0); STG(1, 1, 1);
    asm volatile("s_waitcnt vmcnt(4)" ::: "memory");
    __builtin_amdgcn_s_barrier();

    half8 a[8], b0[4], b1[4];
    for (int i = 0; i < NIT; ++i){
        const int t0 = 2 * i, t1 = 2 * i + 1;
        const bool more = (i + 1 < NIT);
        // ----- K-tile t0 (buf0) -----
        LDA_(a, t0, 0); LDB_(b0, t0, 0);            // ph1: 12 reads
        STG(0, t1, 0);
        SYNC1; MM(a, b0, 0, 0); SYNC2;
        LDB_(b1, t0, 1);                             // ph2: 4 reads
        STG(0, t1, 1);
        SYNC1; MM(a, b1, 0, 1); SYNC2;
        LDA_(a, t0, 1);                              // ph3: 8 reads
        if (more) STG(1, t0 + 2, 0);
        SYNC1; MM(a, b1, 1, 1); SYNC2;
        if (more) STG(1, t0 + 2, 1);                 // ph4: 0 reads
        if (more) asm volatile("s_waitcnt vmcnt(4)" ::: "memory");
        else      asm volatile("s_waitcnt vmcnt(0)" ::: "memory");
        SYNC1; MM(a, b0, 1, 0); SYNC2;
        // ----- K-tile t1 (buf1) -----
        LDA_(a, t1, 0); LDB_(b0, t1, 0);            // ph5
        if (more) STG(0, t0 + 2, 0);
        SYNC1; MM(a, b0, 0, 0); SYNC2;
        LDB_(b1, t1, 1);                             // ph6
        if (more) STG(0, t0 + 2, 1);
        SYNC1; MM(a, b1, 0, 1); SYNC2;
        LDA_(a, t1, 1);                              // ph7
        if (more) STG(1, t1 + 2, 0);
        SYNC1; MM(a, b1, 1, 1); SYNC2;
        if (more) STG(1, t1 + 2, 1);                 // ph8
        if (more) asm volatile("s_waitcnt vmcnt(4)" ::: "memory");
        else      asm volatile("s_waitcnt vmcnt(0)" ::: "memory");
        SYNC1; MM(a, b0, 1, 0); SYNC2;
    }

    // Epilogue. C/D frag mapping: col = lane&15, row = (lane>>4)*4 + reg.
#pragma unroll
    for (int m = 0; m < 8; m++){
        const int rb = row0 + wr + m * 16 + hi * 4;
#pragma unroll
        for (int n = 0; n < 4; n++){
            const int c = col0 + wc + n * 16 + lr;
            const float bc = (BIASM == 1) ? bias[c] : 0.f;
#pragma unroll
            for (int q = 0; q < 4; q++){
                const int r = rb + q;
                float v = acc[m][n][q] + bc;
                if (BIASM == 2) v += bias[r];
                const size_t idx = (size_t)r * ldc + c;
                if (EPI == 0) of[idx] = v;
                else if (EPI == 1) oh[idx] = f2h(v);
                else { const u16 hh = f2h(v); oh[idx] = hh; oh[idx + 1024] = f2h(v - h2f(hh)); }
            }
        }
    }
}

// Fused Q linear + K linear (K-cat, K=2048), product-interleaved per XCD chunk.
__global__ __launch_bounds__(512, 1) void lin_qk_k(
    const u16* __restrict__ rc_h, const u16* __restrict__ ri_hl,
    const u16* __restrict__ Wq_h, const u16* __restrict__ Wk_h,
    const float* __restrict__ bq, const float* __restrict__ bk,
    u16* __restrict__ Q_h, u16* __restrict__ Kcat)
{
    __shared__ __align__(16) u16 sh[65536];      // 128KB
    const int nwg = gridDim.x, chunk = nwg >> 3;
    const int swz = ((int)blockIdx.x & 7) * chunk + ((int)blockIdx.x >> 3);
    const int p = swz & 1, t = swz >> 1;         // t in [0,128): by<32, bx<4
    if (p == 0) {   // Q = rc @ Wq^T + bq -> f16 [8192][1024]
        gemm8<1, 1, false>(rc_h, Wq_h, bq, nullptr, Q_h,
                           t >> 2, t & 3, 1024, 1024, 1024, 1024, sh);
    } else {        // K = ri_hl @ [Wk|Wk]^T + bk -> f16 hi/lo into Kcat [8192][2048]
        gemm8<2, 1, false>(ri_hl, Wk_h, bk, nullptr, Kcat,
                           t >> 2, t & 3, 2048, 1024, 2048, 2048, sh);
    }
}

// Fused batched QK^T (K-cat, K=2048, A=[Q|Q] wrapped) + V^T linear.
// Vt writes the rc_h slot (rc_h dead after lin_qk).
__global__ __launch_bounds__(512, 1) void qkt_vt_k(
    const u16* __restrict__ Q_h, const u16* __restrict__ Kcat,
    const u16* __restrict__ ri_hl, const u16* __restrict__ Wv_h,
    const float* __restrict__ bv,
    float* __restrict__ wts, u16* __restrict__ Vt)
{
    __shared__ __align__(16) u16 sh[65536];
    const int nwg = gridDim.x, chunk = nwg >> 3;
    const int swz = ((int)blockIdx.x & 7) * chunk + ((int)blockIdx.x >> 3);
    const int p = swz & 1, t = swz >> 1;
    if (p == 0) {   // S[b] = [Q|Q] @ Kcat^T -> f32 logits
        const int z = t >> 4, rem = t & 15;      // by<4, bx<4
        gemm8<0, 0, true>(Q_h + (size_t)z * 1048576, Kcat + (size_t)z * 2097152,
                          nullptr, wts + (size_t)z * 1048576, nullptr,
                          rem >> 2, rem & 3, 1024, 2048, 1024, 2048, sh);
    } else {        // V^T = Wv @ ri_h^T + bv(row) -> f16 [1024][8192]
        gemm8<1, 2, false>(Wv_h, ri_hl, bv, nullptr, Vt,
                           t >> 5, t & 31, 1024, 2048, 8192, 1024, sh);
    }
}

// Batched AV: out[b] = W[b] @ V[b]; B rows are Vt rows (d), ldb=8192, col base z*1024.
__global__ __launch_bounds__(512, 1) void av_k(
    const u16* __restrict__ W_h, const u16* __restrict__ Vt, float* __restrict__ outp)
{
    __shared__ __align__(16) u16 sh[65536];
    const int nwg = gridDim.x, chunk = nwg >> 3;
    const int wg = ((int)blockIdx.x & 7) * chunk + ((int)blockIdx.x >> 3);
    const int z = wg >> 4, rem = wg & 15;        // by<4, bx<4
    gemm8<0, 0, false>(W_h + (size_t)z * 1048576, Vt + (size_t)z * 1024,
                       nullptr, outp + (size_t)z * 1048576, nullptr,
                       rem >> 2, rem & 3, 1024, 8192, 1024, 1024, sh);
}

// Fused scale (x *= rsqrt(Kh+Kl)) + row softmax over 1024 cols, in place,
// plus f16 copy of the weights. One 256-thread block per row.
__global__ __launch_bounds__(256)
void softmax_scale_k(float* __restrict__ W, const u16* __restrict__ Kcat, u16* __restrict__ Wh)
{
    const long row = blockIdx.x;
    float* p = W + (row << 10);
    const int tid = threadIdx.x;

    float4 v = ((const float4*)p)[tid];
    const ushort4 kh = ((const ushort4*)(Kcat + (row << 11)))[tid];
    const ushort4 kl = ((const ushort4*)(Kcat + (row << 11) + 1024))[tid];
    v.x *= rsqrtf(h2f(kh.x) + h2f(kl.x));
    v.y *= rsqrtf(h2f(kh.y) + h2f(kl.y));
    v.z *= rsqrtf(h2f(kh.z) + h2f(kl.z));
    v.w *= rsqrtf(h2f(kh.w) + h2f(kl.w));

    float m = fmaxf(fmaxf(v.x, v.y), fmaxf(v.z, v.w));
#pragma unroll
    for (int o = 32; o >= 1; o >>= 1) m = fmaxf(m, __shfl_xor(m, o));
    __shared__ float sm[4];
    const int wid = tid >> 6, lane = tid & 63;
    if (lane == 0) sm[wid] = m;
    __syncthreads();
    m = fmaxf(fmaxf(sm[0], sm[1]), fmaxf(sm[2], sm[3]));

    v.x = __expf(v.x - m); v.y = __expf(v.y - m);
    v.z = __expf(v.z - m); v.w = __expf(v.w - m);
    float s = v.x + v.y + v.z + v.w;
#pragma unroll
    for (int o = 32; o >= 1; o >>= 1) s += __shfl_xor(s, o);
    __shared__ float ss[4];
    if (lane == 0) ss[wid] = s;
    __syncthreads();
    s = ss[0] + ss[1] + ss[2] + ss[3];

    const float inv = 1.0f / s;
    v.x *= inv; v.y *= inv; v.z *= inv; v.w *= inv;
    ((float4*)p)[tid] = v;

    ushort4 ub;
    ub.x = f2h(v.x); ub.y = f2h(v.y); ub.z = f2h(v.z); ub.w = f2h(v.w);
    ((ushort4*)(Wh + (row << 10)))[tid] = ub;
}

// ri f32 -> ri_hl [8192][2048] (hi in cols 0-1023, exact residual lo in 1024-2047).
__global__ __launch_bounds__(256)
void conv_split_k(const float4* __restrict__ x, u16* __restrict__ dst, int n4)
{
    const int i = blockIdx.x * 256 + threadIdx.x;
    if (i >= n4) return;
    const int row = i >> 8, c4 = i & 255;
    const float4 v = x[i];
    ushort4 hh, ll;
    hh.x = f2h(v.x); ll.x = f2h(v.x - h2f(hh.x));
    hh.y = f2h(v.y); ll.y = f2h(v.y - h2f(hh.y));
    hh.z = f2h(v.z); ll.z = f2h(v.z - h2f(hh.z));
    hh.w = f2h(v.w); ll.w = f2h(v.w - h2f(hh.w));
    ((ushort4*)(dst + (size_t)row * 2048))[c4] = hh;
    ((ushort4*)(dst + (size_t)row * 2048 + 1024))[c4] = ll;
}

// rc (2M float4) + Wq + Wk + Wv (256K float4 each) in one launch: 11264 blocks.
__global__ __launch_bounds__(256)
void conv_plain4_k(const float4* __restrict__ x0, ushort4* __restrict__ y0,
                   const float4* __restrict__ x1, ushort4* __restrict__ y1,
                   const float4* __restrict__ x2, ushort4* __restrict__ y2,
                   const float4* __restrict__ x3, ushort4* __restrict__ y3)
{
    const long i = (long)blockIdx.x * 256 + threadIdx.x;
    const long n0 = 2097152, n1 = 262144;
    const float4* x; ushort4* y; long j;
    if (i < n0)            { x = x0; y = y0; j = i; }
    else if (i < n0 + n1)  { x = x1; y = y1; j = i - n0; }
    else if (i < n0 + 2*n1){ x = x2; y = y2; j = i - n0 - n1; }
    else                   { x = x3; y = y3; j = i - n0 - 2*n1; }
    const float4 v = x[j];
    ushort4 o;
    o.x = f2h(v.x); o.y = f2h(v.y); o.z = f2h(v.z); o.w = f2h(v.w);
    y[j] = o;
}

extern "C" void kernel_launch(void* const* d_in, const int* in_sizes, int n_in,
                              void* d_out, int out_size, void* d_ws, size_t ws_size,
                              hipStream_t stream)
{
    const float* rc = (const float*)d_in[0];
    const float* ri = (const float*)d_in[1];
    const float* Wq = (const float*)d_in[3];
    const float* bq = (const float*)d_in[4];
    const float* Wk = (const float*)d_in[5];
    const float* bk = (const float*)d_in[6];
    const float* Wv = (const float*)d_in[7];
    const float* bv = (const float*)d_in[8];

    const long M8 = 8192 * 1024L;
    const long M1 = 1024 * 1024L;

    u16* ws    = (u16*)d_ws;
    u16* ri_hl = ws;                 // 16M u16: [8192][2048] = [ri_h | ri_l]; reused as W_h
    u16* rc_h  = ws + 2 * M8;        // 8M; reused as Vt after lin_qk
    u16* Kcat  = ws + 3 * M8;        // 16M: [8192][2048] = [Kh | Kl]
    u16* Wq_h  = ws + 5 * M8;        // 1M
    u16* Wk_h  = Wq_h + M1;          // 1M
    u16* Wv_h  = Wk_h + M1;          // 1M   (total 43M u16 = 86MB)

    float* outp = (float*)d_out;            // output [8,1024,1024]
    float* wts  = outp + M8;                // attention_weights
    u16*   Q_h  = (u16*)d_out;              // scratch in outp half, dead before AV
    u16*   Vt   = rc_h;                     // V^T [1024][8192]
    u16*   W_h  = ri_hl;                    // f16 weights [8192][1024]

    // conversions
    conv_split_k<<<8192, 256, 0, stream>>>((const float4*)ri, ri_hl, (int)(M8 / 4));
    conv_plain4_k<<<11264, 256, 0, stream>>>(
        (const float4*)rc, (ushort4*)rc_h, (const float4*)Wq, (ushort4*)Wq_h,
        (const float4*)Wk, (ushort4*)Wk_h, (const float4*)Wv, (ushort4*)Wv_h);

    // Q linear + K linear (K-cat) fused: 256 blocks x 512 thr
    lin_qk_k<<<256, 512, 0, stream>>>(rc_h, ri_hl, Wq_h, Wk_h, bq, bk, Q_h, Kcat);

    // batched QK^T (K-cat) + V^T linear fused: 256 blocks x 512 thr
    qkt_vt_k<<<256, 512, 0, stream>>>(Q_h, Kcat, ri_hl, Wv_h, bv, wts, Vt);

    // scale by rsqrt(K) + softmax + f16 weights copy (W_h overwrites ri_hl, now dead)
    softmax_scale_k<<<8192, 256, 0, stream>>>(wts, Kcat, W_h);

    // output = weights @ V
    av_k<<<128, 512, 0, stream>>>(W_h, Vt, outp);
}

// Round 9
// 164.689 us; speedup vs baseline: 1.2380x; 1.2380x over previous
//
#include <hip/hip_runtime.h>
#include <hip/hip_fp16.h>
#include <math.h>

typedef unsigned short u16;
typedef __attribute__((ext_vector_type(8))) _Float16 half8;
typedef __attribute__((ext_vector_type(4))) float f32x4;

#define ASLOT 4096    // 128x32 f16 tile elems
#define SLOT  12288   // ring slot elems (A 128x32 + B 256x32 = 24KB)

__device__ __forceinline__ u16 f2h(float f){ __half h=__float2half(f); u16 r; __builtin_memcpy(&r,&h,2); return r; }
__device__ __forceinline__ float h2f(u16 u){ __half h; __builtin_memcpy(&h,&u,2); return __half2float(h); }

// Stage a ROWSx32 f16 tile into LDS (linear dest, lane order). Fetched k-chunk
// is pre-swizzled (c ^= (row>>1)&3) so swizzled ds_reads see correct data while
// global_load_lds writes stay linear (both-sides rule). WRAP: k mod 1024
// (K-concatenation: [Q|Q] @ [Kh|Kl]^T needs A's k wrapped).
template<int ROWS, bool WRAP>
__device__ __forceinline__ void stage_tile(const u16* __restrict__ G, int rowbase, int ldg,
                                           int k0, u16* Ls, int tid){
#pragma unroll
    for (int p = 0; p < ROWS / 64; ++p){
        const int lin = tid + p * 256;
        const int row = lin >> 2;
        const int cg  = ((lin & 3) ^ ((row >> 1) & 3)) * 8;
        const int kk  = WRAP ? (k0 & 1023) : k0;
        const u16* g = G + (size_t)(rowbase + row) * ldg + (kk + cg);
        __builtin_amdgcn_global_load_lds(
            (__attribute__((address_space(1))) void*)g,
            (__attribute__((address_space(3))) void*)(Ls + (size_t)lin * 8), 16, 0, 0);
    }
}

// 128x256 block tile, single product C = A @ B^T. 4 waves, per-wave 64x128 acc
// (4m x 8n fragments): 32 MFMA per barrier-pair, 375 B LDS-read per MFMA.
// Ring: 3 slots, depth-2 prefetch, counted vmcnt (never 0 mid-loop), raw
// s_barriers. Hazards: stage(t+2)->slot s issued after barrier2(t-1)
// rendezvous => all reads of s complete; vmcnt before barrier1 => stage(t)
// landed on all waves.
// EPI: 0=f32, 1=f16, 2=f16 hi/lo split into cols c and c+1024 (ldc=2048).
// BIASM: 0=none, 1=col bias[c], 2=row bias[r].
template<int EPI, int BIASM, bool AWRAP>
__device__ __forceinline__ void gemm_core(
    const u16* __restrict__ A, const u16* __restrict__ B,
    const float* __restrict__ bias,
    float* __restrict__ of, u16* __restrict__ oh,
    int by, int bx, int lda, int ldb, int ldc, int K, u16* sh)
{
    const int tid  = threadIdx.x;
    const int lane = tid & 63, wv = tid >> 6;
    const int wr = (wv >> 1) * 64;        // wave rows: 0 or 64
    const int wc = (wv & 1) * 128;        // wave cols: 0 or 128
    const int row0 = by * 128, col0 = bx * 256;
    const int lr = lane & 15, hi = lane >> 4;
    const int co = (hi ^ ((lr >> 1) & 3)) * 8;   // swizzled k-chunk offset

    f32x4 acc[4][8];
#pragma unroll
    for (int m = 0; m < 4; m++)
#pragma unroll
        for (int n = 0; n < 8; n++) acc[m][n] = (f32x4){0.f, 0.f, 0.f, 0.f};

    auto stage_set = [&](int buf, int k0){
        u16* s = sh + buf * SLOT;
        stage_tile<128, AWRAP>(A, row0, lda, k0, s, tid);
        stage_tile<256, false>(B, col0, ldb, k0, s + ASLOT, tid);
    };

    const int NIT = K >> 5;
    stage_set(0, 0);
    stage_set(1, 32);
    int bufs = 2, bufr = 0;
    for (int t = 0; t < NIT; ++t){
        if (t + 2 < NIT){ stage_set(bufs, (t + 2) << 5); bufs = (bufs + 1 == 3) ? 0 : bufs + 1; }
        const int rem = NIT - 1 - t;     // stage-sets allowed in flight after wait
        if (rem >= 2)      asm volatile("s_waitcnt vmcnt(12)" ::: "memory");  // 2 sets x 6 loads
        else if (rem == 1) asm volatile("s_waitcnt vmcnt(6)" ::: "memory");
        else               asm volatile("s_waitcnt vmcnt(0)" ::: "memory");
        __builtin_amdgcn_s_barrier();            // all waves' stage(t) landed
        __builtin_amdgcn_sched_barrier(0);       // pin reads below the barrier

        const u16* s = sh + bufr * SLOT;
        bufr = (bufr + 1 == 3) ? 0 : bufr + 1;

        half8 a[4], b[8];
#pragma unroll
        for (int m = 0; m < 4; m++) a[m] = *(const half8*)&s[(wr + m * 16 + lr) * 32 + co];
#pragma unroll
        for (int n = 0; n < 8; n++) b[n] = *(const half8*)&s[ASLOT + (wc + n * 16 + lr) * 32 + co];
#pragma unroll
        for (int m = 0; m < 4; m++)
#pragma unroll
            for (int n = 0; n < 8; n++)
                acc[m][n] = __builtin_amdgcn_mfma_f32_16x16x32_f16(a[m], b[n], acc[m][n], 0, 0, 0);
        __builtin_amdgcn_sched_barrier(0);       // pin reads above barrier2
        __builtin_amdgcn_s_barrier();            // reads of bufr done -> safe to re-stage
    }

    // Epilogue. C/D frag mapping: col = lane&15, row = (lane>>4)*4 + reg.
#pragma unroll
    for (int m = 0; m < 4; m++) {
        const int rb = row0 + wr + m * 16 + hi * 4;
#pragma unroll
        for (int n = 0; n < 8; n++) {
            const int c = col0 + wc + n * 16 + lr;
            const float bc = (BIASM == 1) ? bias[c] : 0.f;
#pragma unroll
            for (int q = 0; q < 4; q++) {
                const int r = rb + q;
                float v = acc[m][n][q] + bc;
                if (BIASM == 2) v += bias[r];
                const size_t idx = (size_t)r * ldc + c;
                if (EPI == 0) of[idx] = v;
                else if (EPI == 1) oh[idx] = f2h(v);
                else { const u16 hh = f2h(v); oh[idx] = hh; oh[idx + 1024] = f2h(v - h2f(hh)); }
            }
        }
    }
}

// Fused Q linear + K linear (both single-product, K=1024 -> balanced),
// product-interleaved per XCD chunk.
__global__ __launch_bounds__(256, 2) void lin_qk_k(
    const u16* __restrict__ rc_h, const u16* __restrict__ ri_h,
    const u16* __restrict__ Wq_h, const u16* __restrict__ Wk_h,
    const float* __restrict__ bq, const float* __restrict__ bk,
    u16* __restrict__ Q_h, u16* __restrict__ Kcat)
{
    __shared__ __align__(16) u16 sh[3 * SLOT];   // 72KB
    const int nwg = gridDim.x, chunk = nwg >> 3;
    const int swz = ((int)blockIdx.x & 7) * chunk + ((int)blockIdx.x >> 3);
    const int p = swz & 1, t = swz >> 1;         // t in [0,256): by<64, bx<4
    if (p == 0) {   // Q = rc @ Wq^T + bq -> f16 [8192][1024]
        gemm_core<1, 1, false>(rc_h, Wq_h, bq, nullptr, Q_h,
                               t >> 2, t & 3, 1024, 1024, 1024, 1024, sh);
    } else {        // K = ri_h @ Wk^T + bk -> f16 hi/lo into Kcat [8192][2048]
        gemm_core<2, 1, false>(ri_h, Wk_h, bk, nullptr, Kcat,
                               t >> 2, t & 3, 1024, 1024, 2048, 1024, sh);
    }
}

// Fused batched QK^T (K-cat, K=2048, A=[Q|Q] wrapped) + V^T linear.
// Vt writes the rc_h slot (rc_h dead after lin_qk).
__global__ __launch_bounds__(256, 2) void qkt_vt_k(
    const u16* __restrict__ Q_h, const u16* __restrict__ Kcat,
    const u16* __restrict__ ri_h, const u16* __restrict__ Wv_h,
    const float* __restrict__ bv,
    float* __restrict__ wts, u16* __restrict__ Vt)
{
    __shared__ __align__(16) u16 sh[3 * SLOT];   // 72KB
    const int nwg = gridDim.x, chunk = nwg >> 3;
    const int swz = ((int)blockIdx.x & 7) * chunk + ((int)blockIdx.x >> 3);
    const int p = swz & 1, t = swz >> 1;
    if (p == 0) {   // S[b] = [Q|Q] @ Kcat^T -> f32 logits
        const int z = t >> 5, rem = t & 31;      // by<8, bx<4
        gemm_core<0, 0, true>(Q_h + (size_t)z * 1048576, Kcat + (size_t)z * 2097152,
                              nullptr, wts + (size_t)z * 1048576, nullptr,
                              rem >> 2, rem & 3, 1024, 2048, 1024, 2048, sh);
    } else {        // V^T = Wv @ ri_h^T + bv(row) -> f16 [1024][8192]
        gemm_core<1, 2, false>(Wv_h, ri_h, bv, nullptr, Vt,
                               t >> 5, t & 31, 1024, 1024, 8192, 1024, sh);
    }
}

// Batched AV: out[b] = W[b] @ V[b]; B rows are Vt rows (d), ldb=8192, col base z*1024.
__global__ __launch_bounds__(256, 2) void av_k(
    const u16* __restrict__ W_h, const u16* __restrict__ Vt, float* __restrict__ outp)
{
    __shared__ __align__(16) u16 sh[3 * SLOT];   // 72KB
    const int nwg = gridDim.x, chunk = nwg >> 3;
    const int wg = ((int)blockIdx.x & 7) * chunk + ((int)blockIdx.x >> 3);
    const int z = wg >> 5, rem = wg & 31;        // by<8, bx<4
    gemm_core<0, 0, false>(W_h + (size_t)z * 1048576, Vt + (size_t)z * 1024,
                           nullptr, outp + (size_t)z * 1048576, nullptr,
                           rem >> 2, rem & 3, 1024, 8192, 1024, 1024, sh);
}

// Fused scale (x *= rsqrt(Kh+Kl)) + row softmax over 1024 cols, in place,
// plus f16 copy of the weights. One 256-thread block per row.
__global__ __launch_bounds__(256)
void softmax_scale_k(float* __restrict__ W, const u16* __restrict__ Kcat, u16* __restrict__ Wh)
{
    const long row = blockIdx.x;
    float* p = W + (row << 10);
    const int tid = threadIdx.x;

    float4 v = ((const float4*)p)[tid];
    const ushort4 kh = ((const ushort4*)(Kcat + (row << 11)))[tid];
    const ushort4 kl = ((const ushort4*)(Kcat + (row << 11) + 1024))[tid];
    v.x *= rsqrtf(h2f(kh.x) + h2f(kl.x));
    v.y *= rsqrtf(h2f(kh.y) + h2f(kl.y));
    v.z *= rsqrtf(h2f(kh.z) + h2f(kl.z));
    v.w *= rsqrtf(h2f(kh.w) + h2f(kl.w));

    float m = fmaxf(fmaxf(v.x, v.y), fmaxf(v.z, v.w));
#pragma unroll
    for (int o = 32; o >= 1; o >>= 1) m = fmaxf(m, __shfl_xor(m, o));
    __shared__ float sm[4];
    const int wid = tid >> 6, lane = tid & 63;
    if (lane == 0) sm[wid] = m;
    __syncthreads();
    m = fmaxf(fmaxf(sm[0], sm[1]), fmaxf(sm[2], sm[3]));

    v.x = __expf(v.x - m); v.y = __expf(v.y - m);
    v.z = __expf(v.z - m); v.w = __expf(v.w - m);
    float s = v.x + v.y + v.z + v.w;
#pragma unroll
    for (int o = 32; o >= 1; o >>= 1) s += __shfl_xor(s, o);
    __shared__ float ss[4];
    if (lane == 0) ss[wid] = s;
    __syncthreads();
    s = ss[0] + ss[1] + ss[2] + ss[3];

    const float inv = 1.0f / s;
    v.x *= inv; v.y *= inv; v.z *= inv; v.w *= inv;
    ((float4*)p)[tid] = v;

    ushort4 ub;
    ub.x = f2h(v.x); ub.y = f2h(v.y); ub.z = f2h(v.z); ub.w = f2h(v.w);
    ((ushort4*)(Wh + (row << 10)))[tid] = ub;
}

// ri (2M float4) + rc (2M) + Wq + Wk + Wv (256K each) in one launch: 19456 blocks.
__global__ __launch_bounds__(256)
void conv_plain5_k(const float4* __restrict__ x0, ushort4* __restrict__ y0,
                   const float4* __restrict__ x1, ushort4* __restrict__ y1,
                   const float4* __restrict__ x2, ushort4* __restrict__ y2,
                   const float4* __restrict__ x3, ushort4* __restrict__ y3,
                   const float4* __restrict__ x4, ushort4* __restrict__ y4)
{
    const long i = (long)blockIdx.x * 256 + threadIdx.x;
    const long n0 = 2097152, n1 = 262144;
    const float4* x; ushort4* y; long j;
    if (i < n0)                 { x = x0; y = y0; j = i; }
    else if (i < 2*n0)          { x = x1; y = y1; j = i - n0; }
    else if (i < 2*n0 + n1)     { x = x2; y = y2; j = i - 2*n0; }
    else if (i < 2*n0 + 2*n1)   { x = x3; y = y3; j = i - 2*n0 - n1; }
    else                        { x = x4; y = y4; j = i - 2*n0 - 2*n1; }
    const float4 v = x[j];
    ushort4 o;
    o.x = f2h(v.x); o.y = f2h(v.y); o.z = f2h(v.z); o.w = f2h(v.w);
    y[j] = o;
}

extern "C" void kernel_launch(void* const* d_in, const int* in_sizes, int n_in,
                              void* d_out, int out_size, void* d_ws, size_t ws_size,
                              hipStream_t stream)
{
    const float* rc = (const float*)d_in[0];
    const float* ri = (const float*)d_in[1];
    const float* Wq = (const float*)d_in[3];
    const float* bq = (const float*)d_in[4];
    const float* Wk = (const float*)d_in[5];
    const float* bk = (const float*)d_in[6];
    const float* Wv = (const float*)d_in[7];
    const float* bv = (const float*)d_in[8];

    const long M8 = 8192 * 1024L;    // 8M elems
    const long M1 = 1024 * 1024L;

    u16* ws   = (u16*)d_ws;
    u16* ri_h = ws;                  // 8M [8192][1024]; reused as W_h after softmax
    u16* rc_h = ws + 1 * M8;         // 8M; reused as Vt after lin_qk
    u16* Kcat = ws + 2 * M8;         // 16M: [8192][2048] = [Kh | Kl]
    u16* Wq_h = ws + 4 * M8;         // 1M
    u16* Wk_h = Wq_h + M1;           // 1M
    u16* Wv_h = Wk_h + M1;           // 1M   (total 35M u16 = 70MB)

    float* outp = (float*)d_out;            // output [8,1024,1024]
    float* wts  = outp + M8;                // attention_weights
    u16*   Q_h  = (u16*)d_out;              // scratch in outp half, dead before AV
    u16*   Vt   = rc_h;                     // V^T [1024][8192]
    u16*   W_h  = ri_h;                     // f16 weights [8192][1024]

    // conversions (all plain f32 -> f16; ri_l no longer needed)
    conv_plain5_k<<<19456, 256, 0, stream>>>(
        (const float4*)ri, (ushort4*)ri_h, (const float4*)rc, (ushort4*)rc_h,
        (const float4*)Wq, (ushort4*)Wq_h, (const float4*)Wk, (ushort4*)Wk_h,
        (const float4*)Wv, (ushort4*)Wv_h);

    // Q linear + K linear fused (both K=1024, balanced): 512 blocks
    lin_qk_k<<<512, 256, 0, stream>>>(rc_h, ri_h, Wq_h, Wk_h, bq, bk, Q_h, Kcat);

    // batched QK^T (K-cat) + V^T linear fused: 512 blocks
    qkt_vt_k<<<512, 256, 0, stream>>>(Q_h, Kcat, ri_h, Wv_h, bv, wts, Vt);

    // scale by rsqrt(K) + softmax + f16 weights copy (W_h overwrites ri_h, now dead)
    softmax_scale_k<<<8192, 256, 0, stream>>>(wts, Kcat, W_h);

    // output = weights @ V
    av_k<<<256, 256, 0, stream>>>(W_h, Vt, outp);
}